// Round 5
// baseline (146.508 us; speedup 1.0000x reference)
//
#include <hip/hip_runtime.h>
#include <stdint.h>

// Rule 110 CA, batch=32, width=16384, 64 iterations, zero boundaries.
// idx = L + 2C + 4R, lookup[k]=(110>>k)&1  ==>  new = (L | C) & ~(L & C & R).
//
// Single fused kernel, trapezoidal width tiling + time-INTERLEAVED stores:
//   - grid (16 tiles, 32 rows), block = 512 threads = 8 waves
//   - every wave computes the full 64-step evolution of its tile in registers
//     (2048-bit state = 1 u32/lane covering cells [s-64, s+1984));
//     wave q stores only the states with t % 8 == q -> stores flow
//     continuously instead of bunching, 16 waves/CU hide the drain
//   - staleness: fake zero carry at working bit 0 corrupts bits [0,t) after
//     t steps; output tile = bits [64,1088), and t <= 64 -> never corrupted
//     (right edge: corruption >= 2048-t > 1088 -> safe)
//   - cross-lane step carries via __ballot; store-side bit redistribution via
//     __shfl; NO LDS, NO barriers -> stores stay in flight across steps
//   - nontemporal 16B stores (write-once data, keep it out of L2); native
//     clang ext_vector_type since __builtin_nontemporal_store rejects
//     HIP_vector_type int4.
// 136 MB of output stores = the HBM-write floor (~22 us at ~6 TB/s).

#define WIDTH  16384
#define BATCH  32
#define ITERS  64
#define TILE   1024
#define NTILE  (WIDTH / TILE)   // 16
#define NWAVE  8                // waves per block; wave q stores t%8==q

typedef int v4i __attribute__((ext_vector_type(4)));

__global__ __launch_bounds__(512) void ca_fused_kernel(
    const float* __restrict__ x, int* __restrict__ out)
{
    const int tid  = threadIdx.x;
    const int lane = tid & 63;
    const int q    = tid >> 6;             // 0..7: which residue of t to store
    const int tile = blockIdx.x;           // 0..15
    const int b    = blockIdx.y;           // 0..31
    const int s    = tile * TILE;

    // ---- pack initial state: lane owns working bits [lane*32, +32) ----
    const int p0 = s - 64 + lane * 32;
    const bool valid = (p0 >= 0) && (p0 < WIDTH);
    const uint32_t vmask = valid ? 0xffffffffu : 0u;

    uint32_t c = 0;
    if (valid) {
        const float4* xv = (const float4*)(x + (size_t)b * WIDTH + p0);
        #pragma unroll
        for (int i = 0; i < 8; ++i) {
            float4 f = xv[i];
            c |= (uint32_t)(f.x >= 0.5f) << (i * 4 + 0);
            c |= (uint32_t)(f.y >= 0.5f) << (i * 4 + 1);
            c |= (uint32_t)(f.z >= 0.5f) << (i * 4 + 2);
            c |= (uint32_t)(f.w >= 0.5f) << (i * 4 + 3);
        }
    }

    int* const out_bt = out + ((size_t)b * (ITERS + 1)) * WIDTH + s;

    for (int t = 0; t <= ITERS; ++t) {
        if ((t & (NWAVE - 1)) == q) {
            // unpack state t -> 1024 int32, 4 coalesced nontemporal 16B/lane
            v4i* ov = (v4i*)(out_bt + (size_t)t * WIDTH);
            #pragma unroll
            for (int j = 0; j < 4; ++j) {
                // lane i's 4 cells = working bits 64 + 256j + 4i .. +3
                uint32_t w   = (uint32_t)__shfl((int)c, 2 + j * 8 + (lane >> 3));
                uint32_t nib = w >> ((lane & 7) * 4);
                v4i v;
                v.x = (int)(nib & 1u);
                v.y = (int)((nib >> 1) & 1u);
                v.z = (int)((nib >> 2) & 1u);
                v.w = (int)((nib >> 3) & 1u);
                __builtin_nontemporal_store(v, ov + j * 64 + lane);
            }
        }
        if (t == ITERS) break;

        // ---- one CA step; cross-lane 1-bit carries via 64-bit ballots ----
        uint64_t A  = __ballot((c & 1u) != 0);   // bit l = LSB of lane l
        uint64_t Bm = __ballot((c >> 31) != 0);  // bit l = MSB of lane l
        uint32_t carryL = (uint32_t)(((Bm << 1) >> lane) & 1ull);
        uint32_t carryR = (uint32_t)(((A  >> 1) >> lane) & 1ull);

        uint32_t l = (c << 1) | carryL;
        uint32_t r = (c >> 1) | (carryR << 31);
        c = ((l | c) & ~(l & c & r)) & vmask;    // vmask: outside array stays 0
    }
}

extern "C" void kernel_launch(void* const* d_in, const int* in_sizes, int n_in,
                              void* d_out, int out_size, void* d_ws, size_t ws_size,
                              hipStream_t stream)
{
    const float* x = (const float*)d_in[0];
    // d_in[1] = rule-110 lookup table -- fixed by setup, baked into the logic.
    (void)d_ws; (void)ws_size;

    dim3 grid(NTILE, BATCH);   // 512 blocks x 8 waves = 4096 waves (~16/CU)
    ca_fused_kernel<<<grid, NWAVE * 64, 0, stream>>>(x, (int*)d_out);
}

// Round 6
// 139.030 us; speedup vs baseline: 1.0538x; 1.0538x over previous
//
#include <hip/hip_runtime.h>
#include <stdint.h>

// Rule 110 CA, batch=32, width=16384, 64 iterations, zero boundaries.
// idx = L + 2C + 4R, lookup[k]=(110>>k)&1  ==>  new = (L | C) & ~(L & C & R).
//
// Single fused kernel, trapezoidal width tiling, 2-way time-interleaved:
//   - grid (16 tiles, 32 rows), block = 128 threads = 2 waves
//   - each wave computes the full 64-step evolution of its tile in registers
//     (2048-bit state = 1 u32/lane covering cells [s-64, s+1984));
//     wave q stores only states with t % 2 == q -> both waves store from the
//     start, stores flow continuously, only 2x redundant VALU (4 waves/CU)
//   - staleness: fake zero carry at working bit 0 corrupts bits [0,t) after
//     t steps; output tile = bits [64,1088) and t <= 64 -> never corrupted
//     (right edge: corruption at >= 2048-t > 1088 -> safe)
//   - cross-lane step carries via __ballot; store-side bit redistribution via
//     __shfl; NO LDS, NO barriers -> the 16 dwordx4 stores per stored step
//     never wait on a vmcnt(0) drain and stay in flight across steps
//   - PLAIN stores (R5 showed nontemporal stores regress ~5 us here)
// 136 MB of output stores = the HBM-write floor (~22 us at ~6 TB/s).

#define WIDTH  16384
#define BATCH  32
#define ITERS  64
#define TILE   1024
#define NTILE  (WIDTH / TILE)   // 16
#define NWAVE  2                // waves per block; wave q stores t%2==q

__global__ __launch_bounds__(128) void ca_fused_kernel(
    const float* __restrict__ x, int* __restrict__ out)
{
    const int tid  = threadIdx.x;
    const int lane = tid & 63;
    const int q    = tid >> 6;             // 0..1: which parity of t to store
    const int tile = blockIdx.x;           // 0..15
    const int b    = blockIdx.y;           // 0..31
    const int s    = tile * TILE;

    // ---- pack initial state: lane owns working bits [lane*32, +32) ----
    const int p0 = s - 64 + lane * 32;
    const bool valid = (p0 >= 0) && (p0 < WIDTH);
    const uint32_t vmask = valid ? 0xffffffffu : 0u;

    uint32_t c = 0;
    if (valid) {
        const float4* xv = (const float4*)(x + (size_t)b * WIDTH + p0);
        #pragma unroll
        for (int i = 0; i < 8; ++i) {
            float4 f = xv[i];
            c |= (uint32_t)(f.x >= 0.5f) << (i * 4 + 0);
            c |= (uint32_t)(f.y >= 0.5f) << (i * 4 + 1);
            c |= (uint32_t)(f.z >= 0.5f) << (i * 4 + 2);
            c |= (uint32_t)(f.w >= 0.5f) << (i * 4 + 3);
        }
    }

    int* const out_bt = out + ((size_t)b * (ITERS + 1)) * WIDTH + s;

    for (int t = 0; t <= ITERS; ++t) {
        if ((t & (NWAVE - 1)) == q) {
            // unpack state t -> 1024 int32, 4 coalesced int4 stores per lane
            int4* ov = (int4*)(out_bt + (size_t)t * WIDTH);
            #pragma unroll
            for (int j = 0; j < 4; ++j) {
                // lane i's 4 cells = working bits 64 + 256j + 4i .. +3
                uint32_t w   = (uint32_t)__shfl((int)c, 2 + j * 8 + (lane >> 3));
                uint32_t nib = w >> ((lane & 7) * 4);
                ov[j * 64 + lane] = make_int4((int)(nib & 1u), (int)((nib >> 1) & 1u),
                                              (int)((nib >> 2) & 1u), (int)((nib >> 3) & 1u));
            }
        }
        if (t == ITERS) break;

        // ---- one CA step; cross-lane 1-bit carries via 64-bit ballots ----
        uint64_t A  = __ballot((c & 1u) != 0);   // bit l = LSB of lane l
        uint64_t Bm = __ballot((c >> 31) != 0);  // bit l = MSB of lane l
        uint32_t carryL = (uint32_t)(((Bm << 1) >> lane) & 1ull);
        uint32_t carryR = (uint32_t)(((A  >> 1) >> lane) & 1ull);

        uint32_t l = (c << 1) | carryL;
        uint32_t r = (c >> 1) | (carryR << 31);
        c = ((l | c) & ~(l & c & r)) & vmask;    // vmask: outside array stays 0
    }
}

extern "C" void kernel_launch(void* const* d_in, const int* in_sizes, int n_in,
                              void* d_out, int out_size, void* d_ws, size_t ws_size,
                              hipStream_t stream)
{
    const float* x = (const float*)d_in[0];
    // d_in[1] = rule-110 lookup table -- fixed by setup, baked into the logic.
    (void)d_ws; (void)ws_size;

    dim3 grid(NTILE, BATCH);   // 512 blocks x 2 waves = 1024 waves (~4/CU)
    ca_fused_kernel<<<grid, NWAVE * 64, 0, stream>>>(x, (int*)d_out);
}